// Round 6
// baseline (143.000 us; speedup 1.0000x reference)
//
#include <hip/hip_runtime.h>

#define NHALF 4096
#define NROWS 8192
#define D 512
#define BM 256
#define BK 64
#define NB (NROWS / BM)            // 32
#define NTRI (NB * (NB + 1) / 2)   // 528 (divisible by 8)
#define CONV_BLOCKS 128
#define LOG2E 1.4426950408889634

typedef __bf16 bf16x8 __attribute__((ext_vector_type(8)));
typedef float  f32x4  __attribute__((ext_vector_type(4)));

__device__ __forceinline__ const float* row_ptr(const float* __restrict__ src,
                                                const float* __restrict__ tgt, int r) {
    return (r < NHALF) ? (src + (size_t)r * D) : (tgt + (size_t)(r - NHALF) * D);
}

// --- Pass A: fused convert fp32->bf16 + rowsq + colsum + sumsq + (last block) bandwidth ---
__global__ __launch_bounds__(256)
void conv_stats(const float* __restrict__ src, const float* __restrict__ tgt,
                __bf16* __restrict__ tot, float* __restrict__ sq,
                float* __restrict__ colsum, double* __restrict__ sumsq,
                unsigned* __restrict__ ticket, float* __restrict__ c2p_out) {
    __shared__ float cs_lds[4][512];
    __shared__ float wssq[4];
    __shared__ int lastFlag;
    __shared__ double red[256];
    int t = threadIdx.x, l = t & 63, w = t >> 6;
    int rbase = blockIdx.x * 64 + w * 16;

    float cs[8] = {0.f, 0.f, 0.f, 0.f, 0.f, 0.f, 0.f, 0.f};
    float ssq = 0.f;

    for (int rr = 0; rr < 16; ++rr) {
        int r = rbase + rr;
        const float* p = row_ptr(src, tgt, r) + l * 8;
        float4 v0 = *(const float4*)p;
        float4 v1 = *(const float4*)(p + 4);
        bf16x8 o;
        o[0] = (__bf16)v0.x; o[1] = (__bf16)v0.y; o[2] = (__bf16)v0.z; o[3] = (__bf16)v0.w;
        o[4] = (__bf16)v1.x; o[5] = (__bf16)v1.y; o[6] = (__bf16)v1.z; o[7] = (__bf16)v1.w;
        *(bf16x8*)&tot[(size_t)r * D + l * 8] = o;
        float s8 = v0.x*v0.x + v0.y*v0.y + v0.z*v0.z + v0.w*v0.w
                 + v1.x*v1.x + v1.y*v1.y + v1.z*v1.z + v1.w*v1.w;
        ssq += s8;
        cs[0] += v0.x; cs[1] += v0.y; cs[2] += v0.z; cs[3] += v0.w;
        cs[4] += v1.x; cs[5] += v1.y; cs[6] += v1.z; cs[7] += v1.w;
        float rsum = s8;
        for (int off = 32; off > 0; off >>= 1) rsum += __shfl_down(rsum, off);
        if (l == 0) sq[r] = rsum;
    }
#pragma unroll
    for (int j = 0; j < 8; ++j) cs_lds[w][l * 8 + j] = cs[j];
    for (int off = 32; off > 0; off >>= 1) ssq += __shfl_down(ssq, off);
    if (l == 0) wssq[w] = ssq;
    __syncthreads();
    int c0 = t * 2;
    float a = cs_lds[0][c0] + cs_lds[1][c0] + cs_lds[2][c0] + cs_lds[3][c0];
    float b = cs_lds[0][c0+1] + cs_lds[1][c0+1] + cs_lds[2][c0+1] + cs_lds[3][c0+1];
    atomicAdd(&colsum[c0], a);
    atomicAdd(&colsum[c0 + 1], b);
    if (t == 0) atomicAdd(sumsq, (double)(wssq[0] + wssq[1] + wssq[2] + wssq[3]));
    __syncthreads();   // all this block's atomics drained (vmcnt) before ticket

    if (t == 0) {
        __threadfence();
        unsigned old = atomicAdd(ticket, 1u);
        lastFlag = (old == CONV_BLOCKS - 1) ? 1 : 0;
    }
    __syncthreads();
    if (lastFlag) {
        // last block computes bandwidth; read cross-block results coherently via atomics
        float ca = atomicAdd(&colsum[t], 0.f);
        float cb = atomicAdd(&colsum[t + 256], 0.f);
        red[t] = (double)ca * ca + (double)cb * cb;
        __syncthreads();
        for (int s = 128; s > 0; s >>= 1) {
            if (t < s) red[t] += red[t + s];
            __syncthreads();
        }
        if (t == 0) {
            double ssqd = atomicAdd(sumsq, 0.0);
            double m = (double)NROWS;
            double sumL2 = 2.0 * m * ssqd - 2.0 * red[0];
            double bw = sumL2 / (m * m - m) / 4.0;   // / KERNEL_MUL^(KERNEL_NUM//2)
            c2p_out[0] = (float)(LOG2E / (16.0 * bw));
        }
    }
}

// --- Pass B: 256x256 MFMA tile, 8 waves, dbuf LDS, 2-phase stage-early ---
__global__ __launch_bounds__(512)
void mmd_main(const __bf16* __restrict__ tot, const float* __restrict__ sq,
              const float* __restrict__ c2p_p, double* __restrict__ S,
              unsigned* __restrict__ ticket, float* __restrict__ out) {
    int b = blockIdx.x;
    int ti = (b & 7) * (NTRI / 8) + (b >> 3);   // XCD swizzle (528 % 8 == 0, bijective)
    int bi = (int)(32.5f - sqrtf(32.5f * 32.5f - 2.0f * (float)ti));
    if (bi < 0) bi = 0;
    while (bi > 0 && bi * NB - bi * (bi - 1) / 2 > ti) --bi;
    while ((bi + 1) * NB - (bi + 1) * bi / 2 <= ti) ++bi;
    int bj = bi + (ti - (bi * NB - bi * (bi - 1) / 2));

    // planar LDS: [dbuf][k-granule plane 0..7][row 0..255][8 bf16]; 64 KB each
    __shared__ __align__(16) __bf16 As[2][8][BM][8];
    __shared__ __align__(16) __bf16 Bs[2][8][BM][8];
    __shared__ float wsum[8];

    int t = threadIdx.x, l = t & 63, w = t >> 6;
    int wr = w >> 2, wc = w & 3;       // 2x4 wave grid; per-wave 128x64 output
    int r0 = l & 15, kg = l >> 4;

    const __bf16* ab = tot + (size_t)(bi * BM) * D;
    const __bf16* bb = tot + (size_t)(bj * BM) * D;

    auto stage = [&](int sel, int kt) {
#pragma unroll
        for (int i = 0; i < 4; ++i) {
            int gidx = i * 512 + t;            // 0..2047 = plane*256 + row
            int plane = gidx >> 8, row = gidx & 255;
            const __bf16* sa = ab + (size_t)row * D + kt * BK + plane * 8;
            const __bf16* sb = bb + (size_t)row * D + kt * BK + plane * 8;
            __builtin_amdgcn_global_load_lds(
                (const __attribute__((address_space(1))) void*)sa,
                (__attribute__((address_space(3))) void*)(&As[sel][0][0][0] + gidx * 8),
                16, 0, 0);
            __builtin_amdgcn_global_load_lds(
                (const __attribute__((address_space(1))) void*)sb,
                (__attribute__((address_space(3))) void*)(&Bs[sel][0][0][0] + gidx * 8),
                16, 0, 0);
        }
    };

    f32x4 acc[8][4];
#pragma unroll
    for (int i = 0; i < 8; ++i)
#pragma unroll
        for (int j = 0; j < 4; ++j)
            acc[i][j] = (f32x4){0.f, 0.f, 0.f, 0.f};

    stage(0, 0);
    __syncthreads();   // drain prologue stage

    for (int kt = 0; kt < 8; ++kt) {
        int cur = kt & 1;
        if (kt < 7) stage(cur ^ 1, kt + 1);   // issue next-tile loads early
#pragma unroll
        for (int ks = 0; ks < 2; ++ks) {
            bf16x8 af[8], bfr[4];
#pragma unroll
            for (int fi = 0; fi < 8; ++fi)
                af[fi] = *(const bf16x8*)&As[cur][ks * 4 + kg][wr * 128 + fi * 16 + r0][0];
#pragma unroll
            for (int fj = 0; fj < 4; ++fj)
                bfr[fj] = *(const bf16x8*)&Bs[cur][ks * 4 + kg][wc * 64 + fj * 16 + r0][0];
#pragma unroll
            for (int fi = 0; fi < 8; ++fi)
#pragma unroll
                for (int fj = 0; fj < 4; ++fj)
                    acc[fi][fj] = __builtin_amdgcn_mfma_f32_16x16x32_bf16(af[fi], bfr[fj], acc[fi][fj], 0, 0, 0);
        }
        __syncthreads();   // compiler drains vmcnt(0) here: next-stage latency hidden under MFMA
    }

    // Epilogue: L2 -> 5-kernel sum via exp2 (1 exp + 4 squarings)
    float c2p = c2p_p[0];
    float tc2 = c2p + c2p;
    float coef = ((bi == bj) ? 1.f : 2.f) * (((bi < NB / 2) == (bj < NB / 2)) ? 1.f : -1.f);

    int jb = bj * BM + wc * 64 + r0;
    float cj[4];
#pragma unroll
    for (int fj = 0; fj < 4; ++fj) cj[fj] = c2p * sq[jb + fj * 16];
    int ib = bi * BM + wr * 128 + (l >> 4) * 4;

    float local = 0.f;
#pragma unroll
    for (int fi = 0; fi < 8; ++fi) {
        float ci[4];
#pragma unroll
        for (int j = 0; j < 4; ++j) ci[j] = c2p * sq[ib + fi * 16 + j];
#pragma unroll
        for (int fj = 0; fj < 4; ++fj) {
#pragma unroll
            for (int j = 0; j < 4; ++j) {
                // arg = -L2 * log2e/(16 bw) = tc2*acc - ci - cj
                float arg = fmaf(acc[fi][fj][j], tc2, -(ci[j] + cj[fj]));
                float u = exp2f(arg);          // e^{-L2/16bw}
                float ks2 = u;
                u *= u; ks2 += u;              // e^{-L2/8bw}
                u *= u; ks2 += u;              // e^{-L2/4bw}
                u *= u; ks2 += u;              // e^{-L2/2bw}
                u *= u; ks2 += u;              // e^{-L2/bw}
                local += ks2;
            }
        }
    }

    for (int off = 32; off > 0; off >>= 1) local += __shfl_down(local, off);
    if (l == 0) wsum[w] = local;
    __syncthreads();
    if (t == 0) {
        float bsum = (wsum[0] + wsum[1] + wsum[2] + wsum[3] +
                      wsum[4] + wsum[5] + wsum[6] + wsum[7]) * coef;
        atomicAdd(S, (double)bsum);
        __threadfence();
        unsigned old = atomicAdd(ticket, 1u);
        if (old == NTRI - 1) {
            double Sv = atomicAdd(S, 0.0);   // coherent read of final total
            out[0] = (float)(Sv / ((double)NHALF * (double)NHALF));
        }
    }
}

extern "C" void kernel_launch(void* const* d_in, const int* in_sizes, int n_in,
                              void* d_out, int out_size, void* d_ws, size_t ws_size,
                              hipStream_t stream) {
    const float* src = (const float*)d_in[0];
    const float* tgt = (const float*)d_in[1];
    float* out = (float*)d_out;
    char* ws = (char*)d_ws;

    // ws layout
    __bf16*   tot     = (__bf16*)ws;                       // 8 MB
    float*    sq      = (float*)(ws + 8388608);            // 32768 B
    float*    colsum  = (float*)(ws + 8388608 + 32768);    // 2048 B
    double*   sumsq   = (double*)(ws + 8388608 + 34816);   // 8 B
    double*   S       = (double*)(ws + 8388608 + 34824);   // 8 B
    unsigned* ticket1 = (unsigned*)(ws + 8388608 + 34832); // 4 B
    unsigned* ticket2 = (unsigned*)(ws + 8388608 + 34836); // 4 B
    float*    c2p     = (float*)(ws + 8388608 + 34840);    // 4 B

    // zero accumulators + tickets (ws poisoned 0xAA, not re-poisoned between replays)
    hipMemsetAsync(ws + 8388608 + 32768, 0, 2072, stream);

    conv_stats<<<CONV_BLOCKS, 256, 0, stream>>>(src, tgt, tot, sq, colsum, sumsq, ticket1, c2p);
    mmd_main<<<NTRI, 512, 0, stream>>>(tot, sq, c2p, S, ticket2, out);
}